// Round 1
// baseline (562.385 us; speedup 1.0000x reference)
//
#include <hip/hip_runtime.h>
#include <math.h>

#define N_ROWS 8192
#define D_DIM  256
#define BI 64
#define BJ 64
#define BK 32
#define PAD 68   // BI + 4: 16B-aligned float4 rows, banks spread (4-way worst on store)

static constexpr float TEMP_INV = 2.0f;  // 1 / 0.5

// ---------------- kernel 1: inverse L2 norms (one wave per row) -------------
__global__ void inv_norm_kernel(const float* __restrict__ out0,
                                const float* __restrict__ out1,
                                float* __restrict__ inv0,
                                float* __restrict__ inv1) {
    int wave = (blockIdx.x * blockDim.x + threadIdx.x) >> 6;  // global wave id
    int lane = threadIdx.x & 63;
    const float* src = (wave < N_ROWS) ? out0 : out1;
    float*       dst = (wave < N_ROWS) ? inv0 : inv1;
    int row = (wave < N_ROWS) ? wave : wave - N_ROWS;

    const float4 v = *reinterpret_cast<const float4*>(src + (size_t)row * D_DIM + lane * 4);
    float ss = v.x * v.x + v.y * v.y + v.z * v.z + v.w * v.w;
    #pragma unroll
    for (int off = 32; off; off >>= 1) ss += __shfl_xor(ss, off);
    if (lane == 0) dst[row] = 1.0f / fmaxf(sqrtf(ss), 1e-12f);
}

// ------- kernel 2: fused GEMM + exp + masked row-sums (atomic accumulate) ---
__global__ __launch_bounds__(256, 2)
void fused_kernel(const float* __restrict__ A,     // out0 [N][D]
                  const float* __restrict__ B,     // out1 [N][D]
                  const float* __restrict__ inv0,
                  const float* __restrict__ inv1,
                  const int*   __restrict__ labels,
                  float* __restrict__ pos_sum,
                  float* __restrict__ all_sum) {
    __shared__ float As[BK][PAD];
    __shared__ float Bs[BK][PAD];

    const int tid = threadIdx.x;
    const int tx = tid & 15;        // 0..15 -> 4 cols each
    const int ty = tid >> 4;        // 0..15 -> 4 rows each
    const int i0 = blockIdx.y * BI;
    const int j0 = blockIdx.x * BJ;

    float acc[4][4] = {};

    for (int k0 = 0; k0 < D_DIM; k0 += BK) {
        // stage tiles: 64 rows x 32 k each; consecutive tids read consecutive k (coalesced)
        #pragma unroll
        for (int it = 0; it < 8; ++it) {
            int idx = tid + it * 256;
            int row = idx >> 5;     // 0..63
            int kk  = idx & 31;     // 0..31
            As[kk][row] = A[(size_t)(i0 + row) * D_DIM + k0 + kk];
            Bs[kk][row] = B[(size_t)(j0 + row) * D_DIM + k0 + kk];
        }
        __syncthreads();

        #pragma unroll
        for (int k = 0; k < BK; ++k) {
            float4 a4 = *reinterpret_cast<const float4*>(&As[k][ty * 4]);
            float4 b4 = *reinterpret_cast<const float4*>(&Bs[k][tx * 4]);
            float av[4] = {a4.x, a4.y, a4.z, a4.w};
            float bv[4] = {b4.x, b4.y, b4.z, b4.w};
            #pragma unroll
            for (int m = 0; m < 4; ++m)
                #pragma unroll
                for (int n = 0; n < 4; ++n)
                    acc[m][n] = fmaf(av[m], bv[n], acc[m][n]);
        }
        __syncthreads();
    }

    // ---- epilogue: exp + mask + per-thread partial row sums ----
    int   rows[4];
    float i0inv[4], i1inv[4];
    int   labr[4], labc[4];
    float pos_p[4] = {}, all_p[4] = {};

    #pragma unroll
    for (int m = 0; m < 4; ++m) {
        rows[m]  = i0 + ty * 4 + m;
        i0inv[m] = inv0[rows[m]];
        labr[m]  = labels[rows[m]];
    }
    #pragma unroll
    for (int n = 0; n < 4; ++n) {
        int c    = j0 + tx * 4 + n;
        i1inv[n] = inv1[c];
        labc[n]  = labels[c];
    }

    #pragma unroll
    for (int m = 0; m < 4; ++m) {
        #pragma unroll
        for (int n = 0; n < 4; ++n) {
            float e = __expf(acc[m][n] * (TEMP_INV * i0inv[m] * i1inv[n]));
            all_p[m] += e;
            pos_p[m] += (labr[m] == labc[n]) ? e : 0.0f;
        }
    }

    // reduce across tx (low 4 lane bits within the wave)
    #pragma unroll
    for (int m = 0; m < 4; ++m) {
        #pragma unroll
        for (int off = 8; off; off >>= 1) {
            all_p[m] += __shfl_xor(all_p[m], off);
            pos_p[m] += __shfl_xor(pos_p[m], off);
        }
    }
    if (tx == 0) {
        #pragma unroll
        for (int m = 0; m < 4; ++m) {
            atomicAdd(&all_sum[rows[m]], all_p[m]);
            atomicAdd(&pos_sum[rows[m]], pos_p[m]);
        }
    }
}

// ---------------- kernel 3: final loss reduction ----------------------------
__global__ void loss_kernel(const float* __restrict__ pos_sum,
                            const float* __restrict__ all_sum,
                            float* __restrict__ out) {
    float acc = 0.0f;
    for (int i = threadIdx.x; i < N_ROWS; i += blockDim.x)
        acc += logf(pos_sum[i] / all_sum[i]);
    #pragma unroll
    for (int off = 32; off; off >>= 1) acc += __shfl_xor(acc, off);
    __shared__ float red[4];
    int wv = threadIdx.x >> 6, lane = threadIdx.x & 63;
    if (lane == 0) red[wv] = acc;
    __syncthreads();
    if (threadIdx.x == 0) out[0] = -(red[0] + red[1] + red[2] + red[3]) / (float)N_ROWS;
}

// ---------------- launch -----------------------------------------------------
extern "C" void kernel_launch(void* const* d_in, const int* in_sizes, int n_in,
                              void* d_out, int out_size, void* d_ws, size_t ws_size,
                              hipStream_t stream) {
    const float* out0   = (const float*)d_in[0];
    const float* out1   = (const float*)d_in[1];
    const int*   labels = (const int*)d_in[2];
    float*       out    = (float*)d_out;

    float* inv0 = (float*)d_ws;
    float* inv1 = inv0 + N_ROWS;
    float* pos  = inv1 + N_ROWS;
    float* alls = pos  + N_ROWS;

    // zero the accumulators (pos, all) every call — deterministic
    hipMemsetAsync(pos, 0, 2 * N_ROWS * sizeof(float), stream);

    inv_norm_kernel<<<2 * N_ROWS / 4, 256, 0, stream>>>(out0, out1, inv0, inv1);

    dim3 grid(N_ROWS / BJ, N_ROWS / BI);
    fused_kernel<<<grid, 256, 0, stream>>>(out0, out1, inv0, inv1, labels, pos, alls);

    loss_kernel<<<1, 256, 0, stream>>>(pos, alls, out);
}

// Round 2
// 172.708 us; speedup vs baseline: 3.2563x; 3.2563x over previous
//
#include <hip/hip_runtime.h>
#include <hip/hip_bf16.h>
#include <math.h>

#define N_ROWS 8192
#define D_DIM  256
#define BM 128
#define BN 128
#define BK 64

typedef __attribute__((ext_vector_type(4))) float f32x4;
typedef __attribute__((ext_vector_type(8))) short bf16x8;

// ---------------- kernel 1: L2-normalize rows, cast to bf16 -----------------
__global__ void norm_cast_kernel(const float* __restrict__ out0,
                                 const float* __restrict__ out1,
                                 __hip_bfloat16* __restrict__ a_bf,
                                 __hip_bfloat16* __restrict__ b_bf) {
    int wave = (blockIdx.x * blockDim.x + threadIdx.x) >> 6;
    int lane = threadIdx.x & 63;
    const float* src        = (wave < N_ROWS) ? out0 : out1;
    __hip_bfloat16* dst     = (wave < N_ROWS) ? a_bf : b_bf;
    int row = (wave < N_ROWS) ? wave : wave - N_ROWS;

    float4 v = *reinterpret_cast<const float4*>(src + (size_t)row * D_DIM + lane * 4);
    float ss = v.x * v.x + v.y * v.y + v.z * v.z + v.w * v.w;
    #pragma unroll
    for (int off = 32; off; off >>= 1) ss += __shfl_xor(ss, off);
    float inv = 1.0f / fmaxf(sqrtf(ss), 1e-12f);

    union { ushort4 u; __hip_bfloat16 h[4]; } o;
    o.h[0] = __float2bfloat16(v.x * inv);
    o.h[1] = __float2bfloat16(v.y * inv);
    o.h[2] = __float2bfloat16(v.z * inv);
    o.h[3] = __float2bfloat16(v.w * inv);
    *reinterpret_cast<ushort4*>(dst + (size_t)row * D_DIM + lane * 4) = o.u;
}

// ------- kernel 2: bf16 MFMA GEMM + exp + masked row-sums -------------------
// 128x128 tile, BK=64, 4 waves in 2x2, each wave 64x64 (4x4 frags of 16x16x32).
// LDS: linear dest for global_load_lds(16B); XOR swizzle byte^((row&7)<<4)
// applied on the GLOBAL source address (write side) and on ds_read (read side).
__global__ __launch_bounds__(256, 2)
void fused_mfma_kernel(const __hip_bfloat16* __restrict__ A,  // normalized out0
                       const __hip_bfloat16* __restrict__ B,  // normalized out1
                       const int* __restrict__ labels,
                       float* __restrict__ pos_sum,
                       float* __restrict__ all_sum) {
    __shared__ __hip_bfloat16 As[BM * BK];   // 16 KB
    __shared__ __hip_bfloat16 Bs[BN * BK];   // 16 KB

    const int tid  = threadIdx.x;
    const int lane = tid & 63;
    const int wid  = tid >> 6;
    const int i0 = blockIdx.y * BM;
    const int j0 = blockIdx.x * BN;
    const int wr = wid >> 1, wc = wid & 1;   // 2x2 wave grid

    // staging constants: chunk = 1024B = 8 rows x 128B; lane l -> phys byte l*16
    const int l8   = lane >> 3;                       // row-in-chunk 0..7
    const int koff = 16 * ((lane & 7) ^ l8);          // pre-swizzled within-row byte

    f32x4 acc[4][4] = {};

    for (int kt = 0; kt < D_DIM / BK; ++kt) {
        // ---- stage: each wave 4 A-chunks + 4 B-chunks of 1KB ----
        #pragma unroll
        for (int cc = 0; cc < 4; ++cc) {
            int c   = wid * 4 + cc;                   // chunk 0..15
            int row = c * 8 + l8;                     // tile row 0..127
            const char* ga = (const char*)A + (((size_t)(i0 + row)) * D_DIM + kt * BK) * 2 + koff;
            const char* gb = (const char*)B + (((size_t)(j0 + row)) * D_DIM + kt * BK) * 2 + koff;
            __builtin_amdgcn_global_load_lds(
                (const __attribute__((address_space(1))) void*)ga,
                (__attribute__((address_space(3))) void*)((char*)As + c * 1024), 16, 0, 0);
            __builtin_amdgcn_global_load_lds(
                (const __attribute__((address_space(1))) void*)gb,
                (__attribute__((address_space(3))) void*)((char*)Bs + c * 1024), 16, 0, 0);
        }
        __syncthreads();

        // ---- compute: 2 K-subtiles of 32, 4x4 MFMAs each ----
        #pragma unroll
        for (int ks = 0; ks < 2; ++ks) {
            bf16x8 af[4], bfv[4];
            #pragma unroll
            for (int m = 0; m < 4; ++m) {
                int row = wr * 64 + m * 16 + (lane & 15);
                int lb  = row * 128 + ks * 64 + (lane >> 4) * 16;
                af[m] = *reinterpret_cast<const bf16x8*>((const char*)As + (lb ^ ((row & 7) << 4)));
            }
            #pragma unroll
            for (int n = 0; n < 4; ++n) {
                int row = wc * 64 + n * 16 + (lane & 15);
                int lb  = row * 128 + ks * 64 + (lane >> 4) * 16;
                bfv[n] = *reinterpret_cast<const bf16x8*>((const char*)Bs + (lb ^ ((row & 7) << 4)));
            }
            #pragma unroll
            for (int m = 0; m < 4; ++m)
                #pragma unroll
                for (int n = 0; n < 4; ++n)
                    acc[m][n] = __builtin_amdgcn_mfma_f32_16x16x32_bf16(af[m], bfv[n], acc[m][n], 0, 0, 0);
        }
        __syncthreads();
    }

    // ---- epilogue: exp + mask + row-sum; C/D: col=lane&15, row=(lane>>4)*4+r ----
    const int lane16 = lane & 15;
    const int kgrp   = lane >> 4;
    int labc[4];
    #pragma unroll
    for (int n = 0; n < 4; ++n) labc[n] = labels[j0 + wc * 64 + n * 16 + lane16];

    #pragma unroll
    for (int m = 0; m < 4; ++m) {
        #pragma unroll
        for (int r = 0; r < 4; ++r) {
            int grow = i0 + wr * 64 + m * 16 + kgrp * 4 + r;
            int labr = labels[grow];
            float allp = 0.0f, posp = 0.0f;
            #pragma unroll
            for (int n = 0; n < 4; ++n) {
                float e = __expf(acc[m][n][r] * 2.0f);   // /TEMPERATURE
                allp += e;
                posp += (labr == labc[n]) ? e : 0.0f;
            }
            #pragma unroll
            for (int off = 1; off < 16; off <<= 1) {
                allp += __shfl_xor(allp, off);
                posp += __shfl_xor(posp, off);
            }
            if (lane16 == 0) {
                atomicAdd(&all_sum[grow], allp);
                atomicAdd(&pos_sum[grow], posp);
            }
        }
    }
}

// ---------------- kernel 3: final loss reduction ----------------------------
__global__ void loss_kernel(const float* __restrict__ pos_sum,
                            const float* __restrict__ all_sum,
                            float* __restrict__ out) {
    float acc = 0.0f;
    for (int i = threadIdx.x; i < N_ROWS; i += blockDim.x)
        acc += logf(pos_sum[i] / all_sum[i]);
    #pragma unroll
    for (int off = 32; off; off >>= 1) acc += __shfl_xor(acc, off);
    __shared__ float red[4];
    int wv = threadIdx.x >> 6, lane = threadIdx.x & 63;
    if (lane == 0) red[wv] = acc;
    __syncthreads();
    if (threadIdx.x == 0) out[0] = -(red[0] + red[1] + red[2] + red[3]) / (float)N_ROWS;
}

// ---------------- launch -----------------------------------------------------
extern "C" void kernel_launch(void* const* d_in, const int* in_sizes, int n_in,
                              void* d_out, int out_size, void* d_ws, size_t ws_size,
                              hipStream_t stream) {
    const float* out0   = (const float*)d_in[0];
    const float* out1   = (const float*)d_in[1];
    const int*   labels = (const int*)d_in[2];
    float*       out    = (float*)d_out;

    __hip_bfloat16* a_bf = (__hip_bfloat16*)d_ws;
    __hip_bfloat16* b_bf = a_bf + (size_t)N_ROWS * D_DIM;
    float* pos  = (float*)(b_bf + (size_t)N_ROWS * D_DIM);
    float* alls = pos + N_ROWS;

    hipMemsetAsync(pos, 0, 2 * N_ROWS * sizeof(float), stream);

    norm_cast_kernel<<<2 * N_ROWS / 4, 256, 0, stream>>>(out0, out1, a_bf, b_bf);

    dim3 grid(N_ROWS / BN, N_ROWS / BM);
    fused_mfma_kernel<<<grid, 256, 0, stream>>>(a_bf, b_bf, labels, pos, alls);

    loss_kernel<<<1, 256, 0, stream>>>(pos, alls, out);
}

// Round 3
// 73.772 us; speedup vs baseline: 7.6233x; 2.3411x over previous
//
#include <hip/hip_runtime.h>
#include <hip/hip_bf16.h>
#include <math.h>

#define N_ROWS 8192
#define D_DIM  256
#define BM 128
#define BN 128
#define JSPLIT 4
#define JRANGE (N_ROWS / JSPLIT)     // 2048
#define NT (JRANGE / BN)             // 16 j-steps per block

typedef __attribute__((ext_vector_type(4))) float f32x4;
typedef __attribute__((ext_vector_type(8))) short bf16x8;

// ---------------- kernel 1: L2-normalize rows, cast to bf16 -----------------
__global__ void norm_cast_kernel(const float* __restrict__ out0,
                                 const float* __restrict__ out1,
                                 __hip_bfloat16* __restrict__ a_bf,
                                 __hip_bfloat16* __restrict__ b_bf) {
    int wave = (blockIdx.x * blockDim.x + threadIdx.x) >> 6;
    int lane = threadIdx.x & 63;
    const float* src        = (wave < N_ROWS) ? out0 : out1;
    __hip_bfloat16* dst     = (wave < N_ROWS) ? a_bf : b_bf;
    int row = (wave < N_ROWS) ? wave : wave - N_ROWS;

    float4 v = *reinterpret_cast<const float4*>(src + (size_t)row * D_DIM + lane * 4);
    float ss = v.x * v.x + v.y * v.y + v.z * v.z + v.w * v.w;
    #pragma unroll
    for (int off = 32; off; off >>= 1) ss += __shfl_xor(ss, off);
    float inv = 1.0f / fmaxf(sqrtf(ss), 1e-12f);

    union { ushort4 u; __hip_bfloat16 h[4]; } o;
    o.h[0] = __float2bfloat16(v.x * inv);
    o.h[1] = __float2bfloat16(v.y * inv);
    o.h[2] = __float2bfloat16(v.z * inv);
    o.h[3] = __float2bfloat16(v.w * inv);
    *reinterpret_cast<ushort4*>(dst + (size_t)row * D_DIM + lane * 4) = o.u;
}

// ------- kernel 2: flash-style fused GEMM + exp + masked row-sums -----------
// 256 blocks = 64 row-tiles x 4 j-splits. 8 waves (2 row x 4 col), wave-tile
// 64x32. A-slice per wave lives in registers (full K=256). B double-buffered
// in LDS, staged with global_load_lds(16B) + XOR swizzle (write via
// pre-swizzled global source, read via swizzled ds_read addr).
__global__ __launch_bounds__(512, 2)
void fused_flash_kernel(const __hip_bfloat16* __restrict__ A,
                        const __hip_bfloat16* __restrict__ B,
                        const int* __restrict__ labels,
                        float* __restrict__ pos_sum,
                        float* __restrict__ all_sum) {
    __shared__ __hip_bfloat16 Bs[2][BN * D_DIM];   // 2 x 64 KB

    const int tid    = threadIdx.x;
    const int lane   = tid & 63;
    const int wid    = tid >> 6;        // 0..7
    const int wr     = wid >> 2;        // 0..1  (row half)
    const int wc     = wid & 3;         // 0..3  (col quarter)
    const int lane16 = lane & 15;
    const int kgrp   = lane >> 4;

    // XCD-chunked logical id: 32 consecutive logical blocks per XCD
    const int logical = (blockIdx.x & 7) * 32 + (blockIdx.x >> 3);
    const int jsplit  = logical >> 6;   // 0..3
    const int rowt    = logical & 63;   // 0..63
    const int i0      = rowt * BM;
    const int jbase   = jsplit * JRANGE;

    // ---- A fragments -> registers (once). row = lane16, k-chunk = kgrp ----
    bf16x8 af[4][8];
    #pragma unroll
    for (int m = 0; m < 4; ++m) {
        const __hip_bfloat16* ap =
            A + (size_t)(i0 + wr * 64 + m * 16 + lane16) * D_DIM + kgrp * 8;
        #pragma unroll
        for (int ks = 0; ks < 8; ++ks)
            af[m][ks] = *reinterpret_cast<const bf16x8*>(ap + ks * 32);
    }

    // labels for my output rows (row = m*16 + kgrp*4 + r)
    int labr[4][4];
    #pragma unroll
    for (int m = 0; m < 4; ++m) {
        int4 v = *reinterpret_cast<const int4*>(labels + i0 + wr * 64 + m * 16 + kgrp * 4);
        labr[m][0] = v.x; labr[m][1] = v.y; labr[m][2] = v.z; labr[m][3] = v.w;
    }

    // ---- B staging: 64 chunks of 1KB (2 rows x 512B each), 8 per wave ----
    auto stage = [&](int buf, int t) {
        const int jrow0 = jbase + t * BN;
        #pragma unroll
        for (int cc = 0; cc < 8; ++cc) {
            int c  = wid * 8 + cc;                  // chunk 0..63 (wave-uniform)
            int gr = jrow0 + c * 2 + (lane >> 5);   // global B row
            const __hip_bfloat16* src =
                B + (size_t)gr * D_DIM + (((lane & 31) ^ (gr & 7)) * 8);
            __builtin_amdgcn_global_load_lds(
                (const __attribute__((address_space(1))) void*)src,
                (__attribute__((address_space(3))) void*)((char*)&Bs[buf][0] + c * 1024),
                16, 0, 0);
        }
    };

    float allp[4][4] = {};
    float posp[4][4] = {};

    stage(0, 0);
    __syncthreads();

    for (int t = 0; t < NT; ++t) {
        const int cur = t & 1;
        if (t + 1 < NT) stage(cur ^ 1, t + 1);

        // ---- compute 128x128 logits tile: 64 MFMA per wave ----
        f32x4 acc[4][2] = {};
        #pragma unroll
        for (int ks = 0; ks < 8; ++ks) {
            bf16x8 bv[2];
            #pragma unroll
            for (int n = 0; n < 2; ++n) {
                int row = wc * 32 + n * 16 + lane16;
                int kb  = ks * 64 + kgrp * 16;
                bv[n] = *reinterpret_cast<const bf16x8*>(
                    (const char*)&Bs[cur][0] + row * 512 + (kb ^ ((row & 7) << 4)));
            }
            #pragma unroll
            for (int m = 0; m < 4; ++m)
                #pragma unroll
                for (int n = 0; n < 2; ++n)
                    acc[m][n] = __builtin_amdgcn_mfma_f32_16x16x32_bf16(af[m][ks], bv[n], acc[m][n], 0, 0, 0);
        }

        // ---- epilogue: exp + mask, accumulate row sums in registers ----
        const int jc    = jbase + t * BN + wc * 32 + lane16;
        const int labc0 = labels[jc];
        const int labc1 = labels[jc + 16];
        #pragma unroll
        for (int m = 0; m < 4; ++m) {
            #pragma unroll
            for (int r = 0; r < 4; ++r) {
                float e0 = __expf(acc[m][0][r] * 2.0f);   // / TEMPERATURE
                float e1 = __expf(acc[m][1][r] * 2.0f);
                allp[m][r] += e0 + e1;
                int lr = labr[m][r];
                posp[m][r] += (lr == labc0 ? e0 : 0.0f) + (lr == labc1 ? e1 : 0.0f);
            }
        }
        __syncthreads();   // drains stage vmcnt + protects Bs[cur] reuse
    }

    // ---- final: reduce across the 16 col-lanes, one atomic per row ----
    #pragma unroll
    for (int m = 0; m < 4; ++m) {
        #pragma unroll
        for (int r = 0; r < 4; ++r) {
            float a = allp[m][r], p = posp[m][r];
            #pragma unroll
            for (int off = 1; off < 16; off <<= 1) {
                a += __shfl_xor(a, off);
                p += __shfl_xor(p, off);
            }
            if (lane16 == 0) {
                int grow = i0 + wr * 64 + m * 16 + kgrp * 4 + r;
                atomicAdd(&all_sum[grow], a);
                atomicAdd(&pos_sum[grow], p);
            }
        }
    }
}

// ---------------- kernel 3: final loss reduction ----------------------------
__global__ void loss_kernel(const float* __restrict__ pos_sum,
                            const float* __restrict__ all_sum,
                            float* __restrict__ out) {
    float acc = 0.0f;
    for (int i = threadIdx.x; i < N_ROWS; i += blockDim.x)
        acc += logf(pos_sum[i] / all_sum[i]);
    #pragma unroll
    for (int off = 32; off; off >>= 1) acc += __shfl_xor(acc, off);
    __shared__ float red[4];
    int wv = threadIdx.x >> 6, lane = threadIdx.x & 63;
    if (lane == 0) red[wv] = acc;
    __syncthreads();
    if (threadIdx.x == 0) out[0] = -(red[0] + red[1] + red[2] + red[3]) / (float)N_ROWS;
}

// ---------------- launch -----------------------------------------------------
extern "C" void kernel_launch(void* const* d_in, const int* in_sizes, int n_in,
                              void* d_out, int out_size, void* d_ws, size_t ws_size,
                              hipStream_t stream) {
    const float* out0   = (const float*)d_in[0];
    const float* out1   = (const float*)d_in[1];
    const int*   labels = (const int*)d_in[2];
    float*       out    = (float*)d_out;

    __hip_bfloat16* a_bf = (__hip_bfloat16*)d_ws;
    __hip_bfloat16* b_bf = a_bf + (size_t)N_ROWS * D_DIM;
    float* pos  = (float*)(b_bf + (size_t)N_ROWS * D_DIM);
    float* alls = pos + N_ROWS;

    hipMemsetAsync(pos, 0, 2 * N_ROWS * sizeof(float), stream);

    norm_cast_kernel<<<2 * N_ROWS / 4, 256, 0, stream>>>(out0, out1, a_bf, b_bf);

    fused_flash_kernel<<<JSPLIT * (N_ROWS / BM), 512, 0, stream>>>(a_bf, b_bf, labels, pos, alls);

    loss_kernel<<<1, 256, 0, stream>>>(pos, alls, out);
}